// Round 8
// baseline (8851.344 us; speedup 1.0000x reference)
//
#include <hip/hip_runtime.h>

// ---------------- output layout (f32 elements) ----------------
#define RAW_OFF 2048L
#define MU_OFF  65538048L
#define LV_OFF  65570816L

// ---------------- ws layout (byte offsets) ----------------
#define WSB_H0    0u          // 32768 double (h ping A) — final h_enc lands here
#define WSB_H1    262144u     // 32768 double
#define WSB_C     524288u     // 32768 double (cell state)
#define WSB_Z0    786432u     // 32768 double
#define WSB_ZPRE  1048576u    // 32*4096 double
#define WSB_HDEC  2097152u    // 2016*1024 f32
#define WSB_GMAX  10354688u   // 2016 u64

// ---------------- device helpers ----------------
__device__ __forceinline__ double sigd(double x){ return 1.0 / (1.0 + exp(-x)); }

__device__ __forceinline__ void tf_round(unsigned &x0, unsigned &x1, int r){
  x0 += x1; x1 = (x1 << r) | (x1 >> (32 - r)); x1 ^= x0;
}

// jax.random.normal(key(42), (32,1024), f32) under jax_threefry_partitionable=True
// (modern JAX default): per-element count pair = (hi32(idx), lo32(idx)) = (0, idx),
// 20-round threefry2x32 with key (0,42), 32-bit combine = bits1 ^ bits2,
// then uniform [-0.99999994, 1) and sqrt(2)*erfinv (XLA Giles f32 polynomial).
__device__ float eps_normal(int idx){
  const unsigned ks0 = 0u, ks1 = 42u, ks2 = 0u ^ 42u ^ 0x1BD11BDAu;
  unsigned x0 = 0u + ks0;              // counts_hi + key1
  unsigned x1 = (unsigned)idx + ks1;   // counts_lo + key2
  tf_round(x0,x1,13); tf_round(x0,x1,15); tf_round(x0,x1,26); tf_round(x0,x1,6);
  x0 += ks1; x1 += ks2 + 1u;
  tf_round(x0,x1,17); tf_round(x0,x1,29); tf_round(x0,x1,16); tf_round(x0,x1,24);
  x0 += ks2; x1 += ks0 + 2u;
  tf_round(x0,x1,13); tf_round(x0,x1,15); tf_round(x0,x1,26); tf_round(x0,x1,6);
  x0 += ks0; x1 += ks1 + 3u;
  tf_round(x0,x1,17); tf_round(x0,x1,29); tf_round(x0,x1,16); tf_round(x0,x1,24);
  x0 += ks1; x1 += ks2 + 4u;
  tf_round(x0,x1,13); tf_round(x0,x1,15); tf_round(x0,x1,26); tf_round(x0,x1,6);
  x0 += ks2; x1 += ks0 + 5u;
  unsigned bits = x0 ^ x1;             // partitionable 32-bit combine
  unsigned fb = (bits >> 9) | 0x3f800000u;
  float f = __uint_as_float(fb) - 1.0f;
  const float lo = -0.99999994f;           // nextafter(-1,0)
  float u = f * 2.0f + lo;                 // (1 - lo) rounds to 2.0f exactly
  u = fmaxf(u, lo);
  float w = -log1pf(-u * u);
  float pl;
  if (w < 5.0f){
    w -= 2.5f;
    pl = 2.81022636e-08f;
    pl = 3.43273939e-07f  + pl * w;
    pl = -3.5233877e-06f  + pl * w;
    pl = -4.39150654e-06f + pl * w;
    pl = 0.00021858087f   + pl * w;
    pl = -0.00125372503f  + pl * w;
    pl = -0.00417768164f  + pl * w;
    pl = 0.246640727f     + pl * w;
    pl = 1.50140941f      + pl * w;
  } else {
    w = sqrtf(w) - 3.0f;
    pl = -0.000200214257f;
    pl = 0.000100950558f  + pl * w;
    pl = 0.00134934322f   + pl * w;
    pl = -0.00367342844f  + pl * w;
    pl = 0.00573950773f   + pl * w;
    pl = -0.0076224613f   + pl * w;
    pl = 0.00943887047f   + pl * w;
    pl = 1.00167406f      + pl * w;
    pl = 2.83297682f      + pl * w;
  }
  return 1.41421356f * (pl * u);
}

// ---------------- GEMM with f64 accumulation, 64x64 tile, 4x4 micro ----------------
// MODE 0: A=embed gather(premises), K=512, N=4096, +bih+bhh -> xpre f32
// MODE 1: A=embed gather(hyp[:, :-1]), K=512, N=4096, +zpre_d(row) -> pre_dec f32
// MODE 2: A=h_dec f32 dense, K=1024, N=32000, +out_b -> raw logits f32 + u64 argmax
template<int MODE>
__global__ __launch_bounds__(256) void gemm_d(
    const float* __restrict__ A, const int* __restrict__ idx,
    const float* __restrict__ B, const float* __restrict__ b1,
    const float* __restrict__ b2, const double* __restrict__ zpre,
    float* __restrict__ C, unsigned long long* __restrict__ gmax,
    int M, int K)
{
  __shared__ double As[16][68];
  __shared__ double Bs[16][68];
  __shared__ unsigned long long kLDS[64];
  const int tid = threadIdx.x;
  const int bx = blockIdx.x, by = blockIdx.y;
  const int lr = tid & 63;
  const int lk = (tid >> 6) * 4;
  int mm = by * 64 + lr; if (mm >= M) mm = M - 1;
  size_t arow;
  if (MODE == 2){
    arow = (size_t)mm * K;
  } else {
    int tok = (MODE == 0) ? idx[mm] : idx[(mm / 63) * 64 + (mm % 63)];
    arow = (size_t)tok * K;
  }
  const size_t brow = (size_t)(bx * 64 + lr) * K;
  const int ty = tid >> 4, tx = tid & 15;
  double acc[4][4];
#pragma unroll
  for (int i = 0; i < 4; ++i)
#pragma unroll
    for (int j = 0; j < 4; ++j) acc[i][j] = 0.0;

  for (int k0 = 0; k0 < K; k0 += 16){
    float4 av = *(const float4*)(A + arow + k0 + lk);
    float4 bv = *(const float4*)(B + brow + k0 + lk);
    __syncthreads();
    As[lk+0][lr] = (double)av.x; As[lk+1][lr] = (double)av.y;
    As[lk+2][lr] = (double)av.z; As[lk+3][lr] = (double)av.w;
    Bs[lk+0][lr] = (double)bv.x; Bs[lk+1][lr] = (double)bv.y;
    Bs[lk+2][lr] = (double)bv.z; Bs[lk+3][lr] = (double)bv.w;
    __syncthreads();
#pragma unroll
    for (int kk = 0; kk < 16; ++kk){
      double ar[4], br[4];
#pragma unroll
      for (int i = 0; i < 4; ++i) ar[i] = As[kk][ty*4+i];
#pragma unroll
      for (int j = 0; j < 4; ++j) br[j] = Bs[kk][tx*4+j];
#pragma unroll
      for (int i = 0; i < 4; ++i)
#pragma unroll
        for (int j = 0; j < 4; ++j) acc[i][j] += ar[i]*br[j];
    }
  }

  if (MODE == 2){
    if (tid < 64) kLDS[tid] = 0ULL;
    __syncthreads();
  }
#pragma unroll
  for (int i = 0; i < 4; ++i){
    int m = by * 64 + ty * 4 + i;
    if (m >= M) continue;
    int n0 = bx * 64 + tx * 4;
    size_t cbase;
    if (MODE == 2){
      int b = m / 63, s = m % 63;
      cbase = (size_t)(b * 64 + s + 1) * 32000;
    } else {
      cbase = (size_t)m * 4096;
    }
    double v[4];
#pragma unroll
    for (int j = 0; j < 4; ++j){
      int n = n0 + j;
      double x = acc[i][j];
      if (MODE == 0)      x += (double)b1[n] + (double)b2[n];
      else if (MODE == 1) x += zpre[(size_t)(m / 63) * 4096 + n];
      else                x += (double)b1[n];
      v[j] = x;
    }
    *(float4*)(C + cbase + n0) =
        make_float4((float)v[0], (float)v[1], (float)v[2], (float)v[3]);
    if (MODE == 2){
      unsigned long long best = 0ULL;
#pragma unroll
      for (int j = 0; j < 4; ++j){
        unsigned long long bits = (unsigned long long)__double_as_longlong(v[j]);
        unsigned long long ob = (bits >> 63) ? ~bits : (bits | 0x8000000000000000ULL);
        unsigned long long pk = (ob & 0xFFFFFFFFFFFF0000ULL) |
                                (unsigned long long)(0xFFFF - (n0 + j));
        best = pk > best ? pk : best;
      }
      atomicMax(&kLDS[ty*4+i], best);
    }
  }
  if (MODE == 2){
    __syncthreads();
    if (tid < 64){
      int m = by * 64 + tid;
      if (m < M) atomicMax(&gmax[m], kLDS[tid]);
    }
  }
}

// ---------------- encoder LSTM step (one launch per t, no grid barrier) ----------------
// 128 blocks x 256 thr; block = 8 units x 32 batch; thread computes all 4 gate dots (f64)
__global__ __launch_bounds__(256) void enc_step(
    const float* __restrict__ W, const float* __restrict__ xpre,
    const double* __restrict__ hc, double* __restrict__ hn,
    double* __restrict__ cbuf, int t)
{
  __shared__ double hl[256][32];
  const int tid = threadIdx.x;
  const int u = tid >> 5, b = tid & 31;
  const int j = blockIdx.x * 8 + u;
  const float* w0p = W + (size_t)(0*1024 + j) * 1024;
  const float* w1p = W + (size_t)(1*1024 + j) * 1024;
  const float* w2p = W + (size_t)(2*1024 + j) * 1024;
  const float* w3p = W + (size_t)(3*1024 + j) * 1024;
  double a0 = 0.0, a1 = 0.0, a2 = 0.0, a3 = 0.0;
  for (int kc = 0; kc < 4; ++kc){
    __syncthreads();
    for (int i = tid; i < 256*32; i += 256){
      int kk = i >> 5, bb = i & 31;
      hl[kk][bb] = hc[(size_t)(kc*256 + kk)*32 + bb];
    }
    __syncthreads();
    const int kb = kc * 256;
    for (int k2 = 0; k2 < 256; k2 += 4){
      float4 w0 = *(const float4*)(w0p + kb + k2);
      float4 w1 = *(const float4*)(w1p + kb + k2);
      float4 w2 = *(const float4*)(w2p + kb + k2);
      float4 w3 = *(const float4*)(w3p + kb + k2);
      double h0 = hl[k2][b], h1 = hl[k2+1][b], h2 = hl[k2+2][b], h3 = hl[k2+3][b];
      a0 += (double)w0.x*h0 + (double)w0.y*h1 + (double)w0.z*h2 + (double)w0.w*h3;
      a1 += (double)w1.x*h0 + (double)w1.y*h1 + (double)w1.z*h2 + (double)w1.w*h3;
      a2 += (double)w2.x*h0 + (double)w2.y*h1 + (double)w2.z*h2 + (double)w2.w*h3;
      a3 += (double)w3.x*h0 + (double)w3.y*h1 + (double)w3.z*h2 + (double)w3.w*h3;
    }
  }
  const size_t xb = (size_t)(b * 64 + t) * 4096;
  a0 += (double)xpre[xb + j];
  a1 += (double)xpre[xb + 1024 + j];
  a2 += (double)xpre[xb + 2048 + j];
  a3 += (double)xpre[xb + 3072 + j];
  double c = cbuf[(size_t)j*32 + b];
  double cn = sigd(a1) * c + sigd(a0) * tanh(a2);
  cbuf[(size_t)j*32 + b] = cn;
  hn[(size_t)j*32 + b] = sigd(a3) * tanh(cn);
}

// ---------------- mu/logvar + reparameterize (f64) ----------------
__global__ __launch_bounds__(256) void mulv_kernel(
    const double* __restrict__ henc, const float* __restrict__ muW,
    const float* __restrict__ lvW, const float* __restrict__ mub,
    const float* __restrict__ lvb, float* __restrict__ out,
    double* __restrict__ z0d)
{
  __shared__ double hl[256][32];
  const int tid = threadIdx.x;
  const int jl = tid >> 5, b = tid & 31;
  const int j = blockIdx.x * 8 + jl;
  const float* wm = muW + (size_t)j * 1024;
  const float* wv = lvW + (size_t)j * 1024;
  double am = 0.0, av = 0.0;
  for (int kc = 0; kc < 4; ++kc){
    __syncthreads();
    for (int i = tid; i < 256*32; i += 256){
      int kk = i >> 5, bb = i & 31;
      hl[kk][bb] = henc[(size_t)(kc*256 + kk)*32 + bb];
    }
    __syncthreads();
    const int kb = kc * 256;
    for (int k2 = 0; k2 < 256; k2 += 4){
      float4 m4 = *(const float4*)(wm + kb + k2);
      float4 v4 = *(const float4*)(wv + kb + k2);
      double h0 = hl[k2][b], h1 = hl[k2+1][b], h2 = hl[k2+2][b], h3 = hl[k2+3][b];
      am += (double)m4.x*h0 + (double)m4.y*h1 + (double)m4.z*h2 + (double)m4.w*h3;
      av += (double)v4.x*h0 + (double)v4.y*h1 + (double)v4.z*h2 + (double)v4.w*h3;
    }
  }
  double mu = am + (double)mub[j];
  double lv = av + (double)lvb[j];
  out[MU_OFF + (size_t)b * 1024 + j] = (float)mu;
  out[LV_OFF + (size_t)b * 1024 + j] = (float)lv;
  double e = (double)eps_normal(b * 1024 + j);
  z0d[(size_t)b * 1024 + j] = mu + e * exp(0.5 * lv);
}

// ---------------- zpre = z0 @ dec_Whh^T + bih + bhh (f64) ----------------
__global__ __launch_bounds__(256) void zpre_kernel(
    const double* __restrict__ z0d, const float* __restrict__ dWhh,
    const float* __restrict__ bih, const float* __restrict__ bhh,
    double* __restrict__ zpred)
{
  const int tid = threadIdx.x;
  const int gl = tid >> 5, b = tid & 31;
  const int g = blockIdx.x * 8 + gl;
  const float* w = dWhh + (size_t)g * 1024;
  const double* z = z0d + (size_t)b * 1024;
  double acc = 0.0;
  for (int k = 0; k < 1024; k += 4){
    float4 w4 = *(const float4*)(w + k);
    acc += (double)w4.x*z[k] + (double)w4.y*z[k+1] + (double)w4.z*z[k+2] + (double)w4.w*z[k+3];
  }
  zpred[(size_t)b * 4096 + g] = acc + (double)bih[g] + (double)bhh[g];
}

// ---------------- decoder gates (f64 math, f32 storage) ----------------
__global__ __launch_bounds__(256) void gates_kernel(
    const float* __restrict__ pre, const double* __restrict__ z0d,
    float* __restrict__ hdec)
{
  int gid = blockIdx.x * 256 + threadIdx.x;   // exactly 2016*1024
  int m = gid >> 10, jj = gid & 1023;
  int b = m / 63;
  size_t base = (size_t)m * 4096;
  double iv = (double)pre[base + jj];
  double fv = (double)pre[base + 1024 + jj];
  double gv = (double)pre[base + 2048 + jj];
  double ov = (double)pre[base + 3072 + jj];
  double z = z0d[(size_t)b * 1024 + jj];
  double c2 = sigd(fv) * z + sigd(iv) * tanh(gv);
  hdec[(size_t)m * 1024 + jj] = (float)(sigd(ov) * tanh(c2));
}

// ---------------- raw_outputs t=0 zero fill ----------------
__global__ void zero_first(float* __restrict__ out){
  int gid = blockIdx.x * 256 + threadIdx.x;   // exactly 32*32000
  int b = gid / 32000, n = gid % 32000;
  out[RAW_OFF + (size_t)b * 2048000 + n] = 0.0f;
}

// ---------------- words (argmax decode) ----------------
__global__ void words_kernel(const unsigned long long* __restrict__ gmax,
                             const int* __restrict__ hyp, float* __restrict__ out)
{
  int q = blockIdx.x * 256 + threadIdx.x;
  if (q >= 2048) return;
  int b = q >> 6, s = q & 63;
  float wv;
  if (s == 0){
    wv = (float)hyp[b * 64];
  } else {
    unsigned long long pk = gmax[b * 63 + s - 1];
    wv = (float)(0xFFFF - (int)(pk & 0xFFFFULL));
  }
  out[q] = wv;
}

// ---------------- launch ----------------
extern "C" void kernel_launch(void* const* d_in, const int* in_sizes, int n_in,
                              void* d_out, int out_size, void* d_ws, size_t ws_size,
                              hipStream_t stream)
{
  const int*   premises = (const int*)d_in[0];
  const int*   hyp      = (const int*)d_in[1];
  const float* embed_W  = (const float*)d_in[3];
  const float* enc_Wih  = (const float*)d_in[4];
  const float* enc_Whh  = (const float*)d_in[5];
  const float* enc_bih  = (const float*)d_in[6];
  const float* enc_bhh  = (const float*)d_in[7];
  const float* mu_W     = (const float*)d_in[8];
  const float* mu_b     = (const float*)d_in[9];
  const float* lv_W     = (const float*)d_in[10];
  const float* lv_b     = (const float*)d_in[11];
  const float* dec_Wih  = (const float*)d_in[12];
  const float* dec_Whh  = (const float*)d_in[13];
  const float* dec_bih  = (const float*)d_in[14];
  const float* dec_bhh  = (const float*)d_in[15];
  const float* out_W    = (const float*)d_in[16];
  const float* out_b    = (const float*)d_in[17];
  float* out = (float*)d_out;
  char*  wsb = (char*)d_ws;

  // zero h ping-pong + cell state (f64) and the argmax accumulators
  hipMemsetAsync(wsb + WSB_H0, 0, 3 * 32768 * 8, stream);
  hipMemsetAsync(wsb + WSB_GMAX, 0, 2016 * 8, stream);

  float* xpre = out + RAW_OFF;      // f32 scratch in raw-logits region (dead before logits)
  dim3 gx(64, 32);
  gemm_d<0><<<gx, 256, 0, stream>>>(embed_W, premises, enc_Wih, enc_bih, enc_bhh,
                                    nullptr, xpre, nullptr, 2048, 512);

  for (int t = 0; t < 64; ++t){
    const double* hc = (const double*)(wsb + ((t & 1) ? WSB_H1 : WSB_H0));
    double*       hn = (double*)(wsb + ((t & 1) ? WSB_H0 : WSB_H1));
    enc_step<<<128, 256, 0, stream>>>(enc_Whh, xpre, hc, hn,
                                      (double*)(wsb + WSB_C), t);
  }
  // 64 steps -> final h in H0

  mulv_kernel<<<128, 256, 0, stream>>>((const double*)(wsb + WSB_H0), mu_W, lv_W,
                                       mu_b, lv_b, out, (double*)(wsb + WSB_Z0));

  zpre_kernel<<<512, 256, 0, stream>>>((const double*)(wsb + WSB_Z0), dec_Whh,
                                       dec_bih, dec_bhh, (double*)(wsb + WSB_ZPRE));

  float* pre_dec = out + RAW_OFF;   // reuse raw region (dead before logits)
  gemm_d<1><<<gx, 256, 0, stream>>>(embed_W, hyp, dec_Wih, nullptr, nullptr,
                                    (const double*)(wsb + WSB_ZPRE), pre_dec,
                                    nullptr, 2016, 512);

  gates_kernel<<<8064, 256, 0, stream>>>(pre_dec, (const double*)(wsb + WSB_Z0),
                                         (float*)(wsb + WSB_HDEC));

  dim3 g2(500, 32);
  gemm_d<2><<<g2, 256, 0, stream>>>((const float*)(wsb + WSB_HDEC), nullptr, out_W,
                                    out_b, nullptr, nullptr, out + RAW_OFF,
                                    (unsigned long long*)(wsb + WSB_GMAX), 2016, 1024);

  zero_first<<<4000, 256, 0, stream>>>(out);

  words_kernel<<<8, 256, 0, stream>>>((const unsigned long long*)(wsb + WSB_GMAX),
                                      hyp, out);
}